// Round 4
// baseline (1885.898 us; speedup 1.0000x reference)
//
#include <hip/hip_runtime.h>
#include <hip/hip_bf16.h>

#define EPS_BN 1e-5f

typedef __bf16 bf16_t;
typedef __bf16 bf16x8 __attribute__((ext_vector_type(8)));
typedef float floatx16 __attribute__((ext_vector_type(16)));

// ---------------- prep: zero stats + wq + pack W fragments ----------------
// wpack layout: ((((layer*2+wn)*4+nt)*16+kt)*64+lane)*8+e
//   lane = (k>>3 & 1)*32 + (col&31); col = wn*128+nt*32+(lane&31); k = kt*16+(lane>>5)*8+e
__global__ __launch_bounds__(256) void prep_kernel(
    const float* __restrict__ q, const float* __restrict__ gw1,
    const float* __restrict__ gb1, const float* __restrict__ g2,
    const float* __restrict__ g3, const float* __restrict__ g4,
    float* __restrict__ sums, float* __restrict__ wq, bf16_t* __restrict__ wpack)
{
    int blk = blockIdx.x, t = threadIdx.x;
    if (blk == 0 && t < 192) sums[t] = 0.f;
    {
        float acc = gb1[t];
        #pragma unroll
        for (int d = 0; d < 11; d++)
            acc = fmaf(q[blk * 11 + d], gw1[(52 + d) * 256 + t], acc);
        wq[blk * 256 + t] = acc;
    }
    for (int idx = blk * 3072 + t; idx < blk * 3072 + 3072; idx += 256) {
        int layer = idx >> 16;
        int rem = idx & 65535;
        int col = rem & 255;
        int k = rem >> 8;
        const float* gw = (layer == 0) ? g2 : ((layer == 1) ? g3 : g4);
        float v = gw[k * 256 + col];
        int wn = col >> 7, nt = (col >> 5) & 3, l31 = col & 31;
        int kt = k >> 4, l2 = (k >> 3) & 1, e = k & 7;
        int lane = l2 * 32 + l31;
        wpack[((((layer * 2 + wn) * 4 + nt) * 16 + kt) * 64 + lane) * 8 + e] = (bf16_t)v;
    }
}

// ---------------- unified conv: stride-2 3x3 + bias + relu (+BN-fold in) ---
// threads = HOUT*OY_PER*(24/CO_PER) = 256; cog = t/(HOUT*OY_PER) wave-uniform.
template<int CIN, int HOUT, int OY_PER, int CO_PER, bool FOLD>
__global__ __launch_bounds__(256) void conv_kernel(
    const float* __restrict__ in, const float* __restrict__ sums_in,
    float prev_n, const float* __restrict__ gamma,
    const float* __restrict__ beta, const float* __restrict__ w,
    const float* __restrict__ bias, float* __restrict__ out,
    float* __restrict__ sums_out)
{
    const int HIN = 2 * HOUT, ROWS = 2 * OY_PER + 3, RW = 2 * HOUT + 2;
    const int TILES = HOUT / OY_PER;
    int b = blockIdx.x / TILES, tile = blockIdx.x % TILES;
    int oy0 = tile * OY_PER;
    __shared__ float tin[CIN][ROWS][RW];
    __shared__ float scf[24], shf[24];
    int t = threadIdx.x;
    if (FOLD) {
        if (t < 24) {
            float m = sums_in[t * 2] / prev_n;
            float var = sums_in[t * 2 + 1] / prev_n - m * m;
            float sc = gamma[t] * rsqrtf(var + EPS_BN);
            scf[t] = sc;
            shf[t] = fmaf(-m, sc, beta[t]);
        }
        __syncthreads();
    }
    const int total = CIN * ROWS * RW;
    int iyb = 2 * oy0 - 1;
    #pragma unroll 2
    for (int idx = t; idx < total; idx += 256) {
        int rx = idx % RW;
        int rem = idx / RW;
        int ry = rem % ROWS;
        int ci = rem / ROWS;
        int iy = iyb + ry, ix = rx - 1;
        float v = 0.f;
        if ((unsigned)iy < (unsigned)HIN && (unsigned)ix < (unsigned)HIN) {
            float raw = in[(b * CIN + ci) * HIN * HIN + iy * HIN + ix];
            v = FOLD ? fmaf(raw, scf[ci], shf[ci]) : raw;
        }
        tin[ci][ry][rx] = v;
    }
    __syncthreads();
    int ox = t % HOUT;
    int oyl = (t / HOUT) % OY_PER;
    int cog = t / (HOUT * OY_PER);            // wave-uniform
    const float* wp = w + cog * CO_PER * CIN * 9;
    float acc[CO_PER];
    #pragma unroll
    for (int r = 0; r < CO_PER; r++) acc[r] = bias[cog * CO_PER + r];
    for (int ci = 0; ci < CIN; ci++)
        #pragma unroll
        for (int ky = 0; ky < 3; ky++)
            #pragma unroll
            for (int kx = 0; kx < 3; kx++) {
                float v = tin[ci][2 * oyl + ky][2 * ox + kx];
                #pragma unroll
                for (int r = 0; r < CO_PER; r++)
                    acc[r] = fmaf(v, wp[(r * CIN + ci) * 9 + ky * 3 + kx], acc[r]);
            }
    int oy = oy0 + oyl;
    float s1[CO_PER], s2[CO_PER];
    #pragma unroll
    for (int r = 0; r < CO_PER; r++) {
        float v = fmaxf(acc[r], 0.f);
        out[((b * 24 + cog * CO_PER + r) * HOUT + oy) * HOUT + ox] = v;
        s1[r] = v;
        s2[r] = v * v;
    }
    int lane = t & 63;
    #pragma unroll
    for (int r = 0; r < CO_PER; r++) {
        float a = s1[r], c2 = s2[r];
        #pragma unroll
        for (int off = 32; off > 0; off >>= 1) {
            a += __shfl_xor(a, off);
            c2 += __shfl_xor(c2, off);
        }
        if (lane == 0) {
            int co = cog * CO_PER + r;
            atomicAdd(&sums_out[co * 2], a);
            atomicAdd(&sums_out[co * 2 + 1], c2);
        }
    }
}

// ---------------- U/V with BN4 folded ----------------
__global__ __launch_bounds__(256) void uv_kernel(
    const float* __restrict__ x4, const float* __restrict__ sums4,
    const float* __restrict__ g4, const float* __restrict__ b4,
    const float* __restrict__ gw1, float* __restrict__ U, float* __restrict__ V)
{
    int b = blockIdx.x >> 2, n0 = (blockIdx.x & 3) * 16;
    __shared__ float o[16][26];
    int t = threadIdx.x;
    for (int idx = t; idx < 16 * 26; idx += 256) {
        int n = idx / 26, f = idx % 26;
        int ng = n0 + n;
        float val;
        if (f < 24) {
            float m = sums4[f * 2] * (1.f / 4096.f);
            float var = sums4[f * 2 + 1] * (1.f / 4096.f) - m * m;
            float sc = g4[f] * rsqrtf(var + EPS_BN);
            float sh = fmaf(-m, sc, b4[f]);
            val = fmaf(x4[(b * 24 + f) * 64 + ng], sc, sh);
        } else if (f == 24) val = (float)(ng >> 3) * 0.125f;
        else                val = (float)(ng & 7) * 0.125f;
        o[n][f] = val;
    }
    __syncthreads();
    float g1u[26], g1v[26];
    #pragma unroll
    for (int f = 0; f < 26; f++) {
        g1u[f] = gw1[f * 256 + t];
        g1v[f] = gw1[(26 + f) * 256 + t];
    }
    for (int n = 0; n < 16; n++) {
        float u = 0.f, v = 0.f;
        #pragma unroll
        for (int f = 0; f < 26; f++) {
            float of = o[n][f];
            u = fmaf(of, g1u[f], u);
            v = fmaf(of, g1v[f], v);
        }
        int ng = n0 + n;
        U[(b * 64 + ng) * 256 + t] = u;
        V[(b * 64 + ng) * 256 + t] = v;
    }
}

// ---------------- fused pair MLP: 256 thr, 2 i's (128 rows), 2 blocks/CU ---
// wave (wm,wn): rows wm*64..+63 (2 mt of 32), cols wn*128..+127 (4 nt of 32).
// B prefetched one k-step ahead; acc 128 AGPR.
__global__ __launch_bounds__(256, 2) void pair_kernel(
    const float* __restrict__ U, const float* __restrict__ V,
    const float* __restrict__ wq, const bf16_t* __restrict__ wpack,
    const float* __restrict__ gb2, const float* __restrict__ gb3,
    const float* __restrict__ gb4, float* __restrict__ partial)
{
    __shared__ __align__(16) bf16_t hA[128][264];
    __shared__ float csum[2][256];
    int blk = blockIdx.x;
    int b = blk >> 5;
    int i0 = (blk & 31) * 2;
    int t = threadIdx.x;

    // ---- build h1: rows ii*64+j, cols t
    {
        float wqc = wq[b * 256 + t];
        float uw0 = U[(b * 64 + i0) * 256 + t] + wqc;
        float uw1 = U[(b * 64 + i0 + 1) * 256 + t] + wqc;
        const float* Vb = V + (b * 64) * 256;
        for (int j = 0; j < 64; j++) {
            float v = Vb[j * 256 + t];
            hA[j][t]      = (bf16_t)fmaxf(uw0 + v, 0.0f);
            hA[64 + j][t] = (bf16_t)fmaxf(uw1 + v, 0.0f);
        }
    }
    __syncthreads();

    int lane = t & 63, wave = t >> 6;
    int wm = wave >> 1, wn = wave & 1;
    int l31 = lane & 31, l2 = lane >> 5;
    int r0 = wm * 64 + l31;
    const floatx16 zero16 = {0.f, 0.f, 0.f, 0.f, 0.f, 0.f, 0.f, 0.f,
                             0.f, 0.f, 0.f, 0.f, 0.f, 0.f, 0.f, 0.f};
    float colsum[4] = {0.f, 0.f, 0.f, 0.f};

    #pragma unroll 1
    for (int layer = 0; layer < 3; layer++) {
        const float* bias = (layer == 0) ? gb2 : ((layer == 1) ? gb3 : gb4);
        const bf16_t* Wb = wpack + (size_t)((layer * 2 + wn) * 4) * 16 * 64 * 8;
        float bcol[4];
        #pragma unroll
        for (int nt = 0; nt < 4; nt++)
            bcol[nt] = bias[wn * 128 + nt * 32 + l31];

        floatx16 acc[2][4];
        #pragma unroll
        for (int mt = 0; mt < 2; mt++)
            #pragma unroll
            for (int nt = 0; nt < 4; nt++) acc[mt][nt] = zero16;

        bf16x8 Bc[4];
        #pragma unroll
        for (int nt = 0; nt < 4; nt++)
            Bc[nt] = *(const bf16x8*)(Wb + ((nt * 16) * 64 + lane) * 8);

        #pragma unroll
        for (int ks = 0; ks < 16; ks++) {
            bf16x8 Bn[4];
            if (ks < 15) {
                #pragma unroll
                for (int nt = 0; nt < 4; nt++)
                    Bn[nt] = *(const bf16x8*)(Wb + ((nt * 16 + ks + 1) * 64 + lane) * 8);
            }
            bf16x8 a0 = *(const bf16x8*)&hA[r0][ks * 16 + l2 * 8];
            bf16x8 a1 = *(const bf16x8*)&hA[r0 + 32][ks * 16 + l2 * 8];
            #pragma unroll
            for (int nt = 0; nt < 4; nt++) {
                acc[0][nt] = __builtin_amdgcn_mfma_f32_32x32x16_bf16(a0, Bc[nt], acc[0][nt], 0, 0, 0);
                acc[1][nt] = __builtin_amdgcn_mfma_f32_32x32x16_bf16(a1, Bc[nt], acc[1][nt], 0, 0, 0);
            }
            if (ks < 15) {
                #pragma unroll
                for (int nt = 0; nt < 4; nt++) Bc[nt] = Bn[nt];
            }
        }

        if (layer < 2) {
            __syncthreads();  // all waves done reading hA
            #pragma unroll
            for (int mt = 0; mt < 2; mt++)
                #pragma unroll
                for (int nt = 0; nt < 4; nt++) {
                    int col = wn * 128 + nt * 32 + l31;
                    #pragma unroll
                    for (int reg = 0; reg < 16; reg++) {
                        int row = wm * 64 + mt * 32 + (reg & 3) + 8 * (reg >> 2) + 4 * l2;
                        hA[row][col] = (bf16_t)fmaxf(acc[mt][nt][reg] + bcol[nt], 0.0f);
                    }
                }
            __syncthreads();  // writes visible before next layer
        } else {
            #pragma unroll
            for (int nt = 0; nt < 4; nt++) {
                float s = 0.f;
                #pragma unroll
                for (int mt = 0; mt < 2; mt++)
                    #pragma unroll
                    for (int reg = 0; reg < 16; reg++)
                        s += fmaxf(acc[mt][nt][reg] + bcol[nt], 0.0f);
                colsum[nt] += s;
            }
        }
    }

    #pragma unroll
    for (int nt = 0; nt < 4; nt++)
        colsum[nt] += __shfl_xor(colsum[nt], 32);
    if (l2 == 0) {
        #pragma unroll
        for (int nt = 0; nt < 4; nt++)
            csum[wm][wn * 128 + nt * 32 + l31] = colsum[nt];
    }
    __syncthreads();
    partial[blk * 256 + t] = csum[0][t] + csum[1][t];
}

// ---------------- f_phi ----------------
__global__ __launch_bounds__(256) void fphi_kernel(
    const float* __restrict__ partial,
    const float* __restrict__ fw1, const float* __restrict__ fb1,
    const float* __restrict__ fw2, const float* __restrict__ fb2,
    const float* __restrict__ fw3, const float* __restrict__ fb3,
    float* __restrict__ out)
{
    int b = blockIdx.x, t = threadIdx.x;
    __shared__ float g[256], h1[256], h2[256];
    float s = 0.f;
    for (int k = 0; k < 32; k++) s += partial[(b * 32 + k) * 256 + t];
    g[t] = s * (1.0f / 4096.0f);
    __syncthreads();
    float a1 = fb1[t];
    for (int k = 0; k < 256; k++) a1 = fmaf(g[k], fw1[k * 256 + t], a1);
    h1[t] = fmaxf(a1, 0.0f);
    __syncthreads();
    float a2 = fb2[t];
    for (int k = 0; k < 256; k++) a2 = fmaf(h1[k], fw2[k * 256 + t], a2);
    h2[t] = fmaxf(a2, 0.0f);
    __syncthreads();
    if (t < 10) {
        float a3 = fb3[t];
        for (int k = 0; k < 256; k++) a3 = fmaf(h2[k], fw3[k * 10 + t], a3);
        out[b * 10 + t] = a3;
    }
}

extern "C" void kernel_launch(void* const* d_in, const int* in_sizes, int n_in,
                              void* d_out, int out_size, void* d_ws, size_t ws_size,
                              hipStream_t stream)
{
    (void)in_sizes; (void)n_in; (void)out_size; (void)ws_size;
    const float* img = (const float*)d_in[0];
    const float* q   = (const float*)d_in[1];
    const float* cw[4] = {(const float*)d_in[2],  (const float*)d_in[6],
                          (const float*)d_in[10], (const float*)d_in[14]};
    const float* cb[4] = {(const float*)d_in[3],  (const float*)d_in[7],
                          (const float*)d_in[11], (const float*)d_in[15]};
    const float* bg[4] = {(const float*)d_in[4],  (const float*)d_in[8],
                          (const float*)d_in[12], (const float*)d_in[16]};
    const float* bbv[4] = {(const float*)d_in[5],  (const float*)d_in[9],
                           (const float*)d_in[13], (const float*)d_in[17]};
    const float* gw1 = (const float*)d_in[18]; const float* gb1 = (const float*)d_in[19];
    const float* gw2 = (const float*)d_in[20]; const float* gb2 = (const float*)d_in[21];
    const float* gw3 = (const float*)d_in[22]; const float* gb3 = (const float*)d_in[23];
    const float* gw4 = (const float*)d_in[24]; const float* gb4 = (const float*)d_in[25];
    const float* fw1 = (const float*)d_in[26]; const float* fb1 = (const float*)d_in[27];
    const float* fw2 = (const float*)d_in[28]; const float* fb2 = (const float*)d_in[29];
    const float* fw3 = (const float*)d_in[30]; const float* fb3 = (const float*)d_in[31];

    float* ws  = (float*)d_ws;
    float* x1  = ws;                     // 6291456
    float* x2  = x1 + 6291456;           // 1572864
    float* x3  = x2 + 1572864;           // 393216
    float* x4  = x3 + 393216;            // 98304
    float* sums = x4 + 98304;            // 192
    float* U   = sums + 192;             // 1048576
    float* V   = U + 1048576;            // 1048576
    float* wqv = V + 1048576;            // 16384
    float* part = wqv + 16384;           // 524288
    bf16_t* wpack = (bf16_t*)(part + 524288);  // 3*65536 bf16

    prep_kernel<<<64, 256, 0, stream>>>(q, gw1, gb1, gw2, gw3, gw4,
                                        sums, wqv, wpack);
    // conv1: CIN=3, HOUT=64, 2 rows/blk, 12 co/thread
    conv_kernel<3, 64, 2, 12, false><<<2048, 256, 0, stream>>>(
        img, nullptr, 1.f, nullptr, nullptr, cw[0], cb[0], x1, sums + 0);
    // conv2: CIN=24, HOUT=32, 2 rows/blk, 6 co/thread
    conv_kernel<24, 32, 2, 6, true><<<1024, 256, 0, stream>>>(
        x1, sums + 0, 262144.f, bg[0], bbv[0], cw[1], cb[1], x2, sums + 48);
    // conv3: HOUT=16, 4 rows/blk
    conv_kernel<24, 16, 4, 6, true><<<256, 256, 0, stream>>>(
        x2, sums + 48, 65536.f, bg[1], bbv[1], cw[2], cb[2], x3, sums + 96);
    // conv4: HOUT=8, 8 rows/blk
    conv_kernel<24, 8, 8, 6, true><<<64, 256, 0, stream>>>(
        x3, sums + 96, 16384.f, bg[2], bbv[2], cw[3], cb[3], x4, sums + 144);
    uv_kernel<<<256, 256, 0, stream>>>(x4, sums + 144, bg[3], bbv[3], gw1, U, V);
    pair_kernel<<<2048, 256, 0, stream>>>(U, V, wqv, wpack, gb2, gb3, gb4, part);
    fphi_kernel<<<64, 256, 0, stream>>>(part, fw1, fb1, fw2, fb2, fw3, fb3,
                                        (float*)d_out);
}

// Round 5
// 605.071 us; speedup vs baseline: 3.1168x; 3.1168x over previous
//
#include <hip/hip_runtime.h>
#include <hip/hip_bf16.h>

#define EPS_BN 1e-5f

typedef __bf16 bf16_t;
typedef __bf16 bf16x8 __attribute__((ext_vector_type(8)));
typedef float floatx16 __attribute__((ext_vector_type(16)));

// ---------------- prep: wq + pack W fragments ----------------
// wpack layout: ((((layer*2+wn)*4+nt)*16+kt)*64+lane)*8+e
__global__ __launch_bounds__(256) void prep_kernel(
    const float* __restrict__ q, const float* __restrict__ gw1,
    const float* __restrict__ gb1, const float* __restrict__ g2,
    const float* __restrict__ g3, const float* __restrict__ g4,
    float* __restrict__ wq, bf16_t* __restrict__ wpack)
{
    int blk = blockIdx.x, t = threadIdx.x;
    {
        float acc = gb1[t];
        #pragma unroll
        for (int d = 0; d < 11; d++)
            acc = fmaf(q[blk * 11 + d], gw1[(52 + d) * 256 + t], acc);
        wq[blk * 256 + t] = acc;
    }
    for (int idx = blk * 3072 + t; idx < blk * 3072 + 3072; idx += 256) {
        int layer = idx >> 16;
        int rem = idx & 65535;
        int col = rem & 255;
        int k = rem >> 8;
        const float* gw = (layer == 0) ? g2 : ((layer == 1) ? g3 : g4);
        float v = gw[k * 256 + col];
        int wn = col >> 7, nt = (col >> 5) & 3, l31 = col & 31;
        int kt = k >> 4, l2 = (k >> 3) & 1, e = k & 7;
        int lane = l2 * 32 + l31;
        wpack[((((layer * 2 + wn) * 4 + nt) * 16 + kt) * 64 + lane) * 8 + e] = (bf16_t)v;
    }
}

// ---------------- finalize BN stats: P x 48 partials -> scale/shift[48] ----
__global__ __launch_bounds__(256) void fin_kernel(
    const float* __restrict__ part, int P, float inv_n,
    const float* __restrict__ gamma, const float* __restrict__ beta,
    float* __restrict__ scsh)
{
    __shared__ float red[5][48];
    int t = threadIdx.x;
    if (t < 240) {
        int i = t % 48, s = t / 48;
        float acc = 0.f;
        for (int p = s; p < P; p += 5) acc += part[p * 48 + i];
        red[s][i] = acc;
    }
    __syncthreads();
    if (t < 24) {
        float s1 = 0.f, s2 = 0.f;
        #pragma unroll
        for (int s = 0; s < 5; s++) { s1 += red[s][t * 2]; s2 += red[s][t * 2 + 1]; }
        float m = s1 * inv_n;
        float var = s2 * inv_n - m * m;
        float sc = gamma[t] * rsqrtf(var + EPS_BN);
        scsh[t] = sc;
        scsh[24 + t] = fmaf(-m, sc, beta[t]);
    }
}

// ---------------- unified conv: stride-2 3x3 + bias + relu (+BN-fold in) ---
// threads = HOUT*OY_PER*(24/CO_PER) = 256; cog = t/(HOUT*OY_PER) wave-uniform.
// Stats: wave shuffle-reduce + LDS combine -> plain store of 48 partials.
template<int CIN, int HOUT, int OY_PER, int CO_PER, bool FOLD>
__global__ __launch_bounds__(256) void conv_kernel(
    const float* __restrict__ in, const float* __restrict__ scsh_in,
    const float* __restrict__ w, const float* __restrict__ bias,
    float* __restrict__ out, float* __restrict__ part_out)
{
    const int HIN = 2 * HOUT, ROWS = 2 * OY_PER + 3, RW = 2 * HOUT + 2;
    const int TILES = HOUT / OY_PER;
    const int WPC = (HOUT * OY_PER) / 64;      // waves per channel-group
    int b = blockIdx.x / TILES, tile = blockIdx.x % TILES;
    int oy0 = tile * OY_PER;
    __shared__ float tin[CIN][ROWS][RW];
    __shared__ float scf[24], shf[24];
    __shared__ float red[4][CO_PER * 2];
    int t = threadIdx.x;
    if (FOLD) {
        if (t < 24) { scf[t] = scsh_in[t]; shf[t] = scsh_in[24 + t]; }
        __syncthreads();
    }
    const int total = CIN * ROWS * RW;
    int iyb = 2 * oy0 - 1;
    #pragma unroll 2
    for (int idx = t; idx < total; idx += 256) {
        int rx = idx % RW;
        int rem = idx / RW;
        int ry = rem % ROWS;
        int ci = rem / ROWS;
        int iy = iyb + ry, ix = rx - 1;
        float v = 0.f;
        if ((unsigned)iy < (unsigned)HIN && (unsigned)ix < (unsigned)HIN) {
            float raw = in[(b * CIN + ci) * HIN * HIN + iy * HIN + ix];
            v = FOLD ? fmaf(raw, scf[ci], shf[ci]) : raw;
        }
        tin[ci][ry][rx] = v;
    }
    __syncthreads();
    int ox = t % HOUT;
    int oyl = (t / HOUT) % OY_PER;
    int cog = t / (HOUT * OY_PER);            // wave-uniform
    const float* wp = w + cog * CO_PER * CIN * 9;
    float acc[CO_PER];
    #pragma unroll
    for (int r = 0; r < CO_PER; r++) acc[r] = bias[cog * CO_PER + r];
    for (int ci = 0; ci < CIN; ci++)
        #pragma unroll
        for (int ky = 0; ky < 3; ky++)
            #pragma unroll
            for (int kx = 0; kx < 3; kx++) {
                float v = tin[ci][2 * oyl + ky][2 * ox + kx];
                #pragma unroll
                for (int r = 0; r < CO_PER; r++)
                    acc[r] = fmaf(v, wp[(r * CIN + ci) * 9 + ky * 3 + kx], acc[r]);
            }
    int oy = oy0 + oyl;
    float s1[CO_PER], s2[CO_PER];
    #pragma unroll
    for (int r = 0; r < CO_PER; r++) {
        float v = fmaxf(acc[r], 0.f);
        out[((b * 24 + cog * CO_PER + r) * HOUT + oy) * HOUT + ox] = v;
        s1[r] = v;
        s2[r] = v * v;
    }
    int lane = t & 63, w_id = t >> 6;
    #pragma unroll
    for (int r = 0; r < CO_PER; r++) {
        float a = s1[r], c2 = s2[r];
        #pragma unroll
        for (int off = 32; off > 0; off >>= 1) {
            a += __shfl_xor(a, off);
            c2 += __shfl_xor(c2, off);
        }
        if (lane == 0) { red[w_id][r * 2] = a; red[w_id][r * 2 + 1] = c2; }
    }
    __syncthreads();
    if (t < 48) {
        int ch = t >> 1, st = t & 1;
        int cg = ch / CO_PER, r = ch % CO_PER;
        float v = 0.f;
        #pragma unroll
        for (int k = 0; k < WPC; k++) v += red[cg * WPC + k][r * 2 + st];
        part_out[blockIdx.x * 48 + t] = v;
    }
}

// ---------------- U/V with BN4 folded (scale/shift precomputed) ------------
__global__ __launch_bounds__(256) void uv_kernel(
    const float* __restrict__ x4, const float* __restrict__ scsh4,
    const float* __restrict__ gw1, float* __restrict__ U, float* __restrict__ V)
{
    int b = blockIdx.x >> 2, n0 = (blockIdx.x & 3) * 16;
    __shared__ float o[16][26];
    int t = threadIdx.x;
    for (int idx = t; idx < 16 * 26; idx += 256) {
        int n = idx / 26, f = idx % 26;
        int ng = n0 + n;
        float val;
        if (f < 24)
            val = fmaf(x4[(b * 24 + f) * 64 + ng], scsh4[f], scsh4[24 + f]);
        else if (f == 24) val = (float)(ng >> 3) * 0.125f;
        else              val = (float)(ng & 7) * 0.125f;
        o[n][f] = val;
    }
    __syncthreads();
    float g1u[26], g1v[26];
    #pragma unroll
    for (int f = 0; f < 26; f++) {
        g1u[f] = gw1[f * 256 + t];
        g1v[f] = gw1[(26 + f) * 256 + t];
    }
    for (int n = 0; n < 16; n++) {
        float u = 0.f, v = 0.f;
        #pragma unroll
        for (int f = 0; f < 26; f++) {
            float of = o[n][f];
            u = fmaf(of, g1u[f], u);
            v = fmaf(of, g1v[f], v);
        }
        int ng = n0 + n;
        U[(b * 64 + ng) * 256 + t] = u;
        V[(b * 64 + ng) * 256 + t] = v;
    }
}

// ---------------- fused pair MLP: 256 thr, 2 i's (128 rows), 2 blocks/CU ---
__global__ __launch_bounds__(256, 2) void pair_kernel(
    const float* __restrict__ U, const float* __restrict__ V,
    const float* __restrict__ wq, const bf16_t* __restrict__ wpack,
    const float* __restrict__ gb2, const float* __restrict__ gb3,
    const float* __restrict__ gb4, float* __restrict__ partial)
{
    __shared__ __align__(16) bf16_t hA[128][264];
    __shared__ float csum[2][256];
    int blk = blockIdx.x;
    int b = blk >> 5;
    int i0 = (blk & 31) * 2;
    int t = threadIdx.x;

    {
        float wqc = wq[b * 256 + t];
        float uw0 = U[(b * 64 + i0) * 256 + t] + wqc;
        float uw1 = U[(b * 64 + i0 + 1) * 256 + t] + wqc;
        const float* Vb = V + (b * 64) * 256;
        for (int j = 0; j < 64; j++) {
            float v = Vb[j * 256 + t];
            hA[j][t]      = (bf16_t)fmaxf(uw0 + v, 0.0f);
            hA[64 + j][t] = (bf16_t)fmaxf(uw1 + v, 0.0f);
        }
    }
    __syncthreads();

    int lane = t & 63, wave = t >> 6;
    int wm = wave >> 1, wn = wave & 1;
    int l31 = lane & 31, l2 = lane >> 5;
    int r0 = wm * 64 + l31;
    const floatx16 zero16 = {0.f, 0.f, 0.f, 0.f, 0.f, 0.f, 0.f, 0.f,
                             0.f, 0.f, 0.f, 0.f, 0.f, 0.f, 0.f, 0.f};
    float colsum[4] = {0.f, 0.f, 0.f, 0.f};

    #pragma unroll 1
    for (int layer = 0; layer < 3; layer++) {
        const float* bias = (layer == 0) ? gb2 : ((layer == 1) ? gb3 : gb4);
        const bf16_t* Wb = wpack + (size_t)((layer * 2 + wn) * 4) * 16 * 64 * 8;
        float bcol[4];
        #pragma unroll
        for (int nt = 0; nt < 4; nt++)
            bcol[nt] = bias[wn * 128 + nt * 32 + l31];

        floatx16 acc[2][4];
        #pragma unroll
        for (int mt = 0; mt < 2; mt++)
            #pragma unroll
            for (int nt = 0; nt < 4; nt++) acc[mt][nt] = zero16;

        bf16x8 Bc[4];
        #pragma unroll
        for (int nt = 0; nt < 4; nt++)
            Bc[nt] = *(const bf16x8*)(Wb + ((nt * 16) * 64 + lane) * 8);

        #pragma unroll
        for (int ks = 0; ks < 16; ks++) {
            bf16x8 Bn[4];
            if (ks < 15) {
                #pragma unroll
                for (int nt = 0; nt < 4; nt++)
                    Bn[nt] = *(const bf16x8*)(Wb + ((nt * 16 + ks + 1) * 64 + lane) * 8);
            }
            bf16x8 a0 = *(const bf16x8*)&hA[r0][ks * 16 + l2 * 8];
            bf16x8 a1 = *(const bf16x8*)&hA[r0 + 32][ks * 16 + l2 * 8];
            #pragma unroll
            for (int nt = 0; nt < 4; nt++) {
                acc[0][nt] = __builtin_amdgcn_mfma_f32_32x32x16_bf16(a0, Bc[nt], acc[0][nt], 0, 0, 0);
                acc[1][nt] = __builtin_amdgcn_mfma_f32_32x32x16_bf16(a1, Bc[nt], acc[1][nt], 0, 0, 0);
            }
            if (ks < 15) {
                #pragma unroll
                for (int nt = 0; nt < 4; nt++) Bc[nt] = Bn[nt];
            }
        }

        if (layer < 2) {
            __syncthreads();
            #pragma unroll
            for (int mt = 0; mt < 2; mt++)
                #pragma unroll
                for (int nt = 0; nt < 4; nt++) {
                    int col = wn * 128 + nt * 32 + l31;
                    #pragma unroll
                    for (int reg = 0; reg < 16; reg++) {
                        int row = wm * 64 + mt * 32 + (reg & 3) + 8 * (reg >> 2) + 4 * l2;
                        hA[row][col] = (bf16_t)fmaxf(acc[mt][nt][reg] + bcol[nt], 0.0f);
                    }
                }
            __syncthreads();
        } else {
            #pragma unroll
            for (int nt = 0; nt < 4; nt++) {
                float s = 0.f;
                #pragma unroll
                for (int mt = 0; mt < 2; mt++)
                    #pragma unroll
                    for (int reg = 0; reg < 16; reg++)
                        s += fmaxf(acc[mt][nt][reg] + bcol[nt], 0.0f);
                colsum[nt] += s;
            }
        }
    }

    #pragma unroll
    for (int nt = 0; nt < 4; nt++)
        colsum[nt] += __shfl_xor(colsum[nt], 32);
    if (l2 == 0) {
        #pragma unroll
        for (int nt = 0; nt < 4; nt++)
            csum[wm][wn * 128 + nt * 32 + l31] = colsum[nt];
    }
    __syncthreads();
    partial[blk * 256 + t] = csum[0][t] + csum[1][t];
}

// ---------------- f_phi ----------------
__global__ __launch_bounds__(256) void fphi_kernel(
    const float* __restrict__ partial,
    const float* __restrict__ fw1, const float* __restrict__ fb1,
    const float* __restrict__ fw2, const float* __restrict__ fb2,
    const float* __restrict__ fw3, const float* __restrict__ fb3,
    float* __restrict__ out)
{
    int b = blockIdx.x, t = threadIdx.x;
    __shared__ float g[256], h1[256], h2[256];
    float s = 0.f;
    for (int k = 0; k < 32; k++) s += partial[(b * 32 + k) * 256 + t];
    g[t] = s * (1.0f / 4096.0f);
    __syncthreads();
    float a1 = fb1[t];
    for (int k = 0; k < 256; k++) a1 = fmaf(g[k], fw1[k * 256 + t], a1);
    h1[t] = fmaxf(a1, 0.0f);
    __syncthreads();
    float a2 = fb2[t];
    for (int k = 0; k < 256; k++) a2 = fmaf(h1[k], fw2[k * 256 + t], a2);
    h2[t] = fmaxf(a2, 0.0f);
    __syncthreads();
    if (t < 10) {
        float a3 = fb3[t];
        for (int k = 0; k < 256; k++) a3 = fmaf(h2[k], fw3[k * 10 + t], a3);
        out[b * 10 + t] = a3;
    }
}

extern "C" void kernel_launch(void* const* d_in, const int* in_sizes, int n_in,
                              void* d_out, int out_size, void* d_ws, size_t ws_size,
                              hipStream_t stream)
{
    (void)in_sizes; (void)n_in; (void)out_size; (void)ws_size;
    const float* img = (const float*)d_in[0];
    const float* q   = (const float*)d_in[1];
    const float* cw[4] = {(const float*)d_in[2],  (const float*)d_in[6],
                          (const float*)d_in[10], (const float*)d_in[14]};
    const float* cb[4] = {(const float*)d_in[3],  (const float*)d_in[7],
                          (const float*)d_in[11], (const float*)d_in[15]};
    const float* bg[4] = {(const float*)d_in[4],  (const float*)d_in[8],
                          (const float*)d_in[12], (const float*)d_in[16]};
    const float* bbv[4] = {(const float*)d_in[5],  (const float*)d_in[9],
                           (const float*)d_in[13], (const float*)d_in[17]};
    const float* gw1 = (const float*)d_in[18]; const float* gb1 = (const float*)d_in[19];
    const float* gw2 = (const float*)d_in[20]; const float* gb2 = (const float*)d_in[21];
    const float* gw3 = (const float*)d_in[22]; const float* gb3 = (const float*)d_in[23];
    const float* gw4 = (const float*)d_in[24]; const float* gb4 = (const float*)d_in[25];
    const float* fw1 = (const float*)d_in[26]; const float* fb1 = (const float*)d_in[27];
    const float* fw2 = (const float*)d_in[28]; const float* fb2 = (const float*)d_in[29];
    const float* fw3 = (const float*)d_in[30]; const float* fb3 = (const float*)d_in[31];

    float* ws  = (float*)d_ws;
    float* x1  = ws;                      // 6291456
    float* x2  = x1 + 6291456;            // 1572864
    float* x3  = x2 + 1572864;            // 393216
    float* x4  = x3 + 393216;             // 98304
    float* U   = x4 + 98304;              // 1048576
    float* V   = U + 1048576;             // 1048576
    float* wqv = V + 1048576;             // 16384
    float* part = wqv + 16384;            // 524288
    float* p1  = part + 524288;           // 2048*48 = 98304
    float* p2  = p1 + 98304;              // 1024*48 = 49152
    float* p3  = p2 + 49152;              // 256*48 = 12288
    float* p4  = p3 + 12288;              // 64*48 = 3072
    float* scsh1 = p4 + 3072;             // 48
    float* scsh2 = scsh1 + 48;            // 48
    float* scsh3 = scsh2 + 48;            // 48
    float* scsh4 = scsh3 + 48;            // 48
    bf16_t* wpack = (bf16_t*)(scsh4 + 48);  // 3*65536 bf16

    prep_kernel<<<64, 256, 0, stream>>>(q, gw1, gb1, gw2, gw3, gw4, wqv, wpack);
    conv_kernel<3, 64, 2, 12, false><<<2048, 256, 0, stream>>>(
        img, nullptr, cw[0], cb[0], x1, p1);
    fin_kernel<<<1, 256, 0, stream>>>(p1, 2048, 1.f / 262144.f, bg[0], bbv[0], scsh1);
    conv_kernel<24, 32, 2, 6, true><<<1024, 256, 0, stream>>>(
        x1, scsh1, cw[1], cb[1], x2, p2);
    fin_kernel<<<1, 256, 0, stream>>>(p2, 1024, 1.f / 65536.f, bg[1], bbv[1], scsh2);
    conv_kernel<24, 16, 4, 6, true><<<256, 256, 0, stream>>>(
        x2, scsh2, cw[2], cb[2], x3, p3);
    fin_kernel<<<1, 256, 0, stream>>>(p3, 256, 1.f / 16384.f, bg[2], bbv[2], scsh3);
    conv_kernel<24, 8, 8, 6, true><<<64, 256, 0, stream>>>(
        x3, scsh3, cw[3], cb[3], x4, p4);
    fin_kernel<<<1, 256, 0, stream>>>(p4, 64, 1.f / 4096.f, bg[3], bbv[3], scsh4);
    uv_kernel<<<256, 256, 0, stream>>>(x4, scsh4, gw1, U, V);
    pair_kernel<<<2048, 256, 0, stream>>>(U, V, wqv, wpack, gb2, gb3, gb4, part);
    fphi_kernel<<<64, 256, 0, stream>>>(part, fw1, fb1, fw2, fb2, fw3, fb3,
                                        (float*)d_out);
}

// Round 6
// 421.269 us; speedup vs baseline: 4.4767x; 1.4363x over previous
//
#include <hip/hip_runtime.h>
#include <hip/hip_bf16.h>

#define EPS_BN 1e-5f

typedef __bf16 bf16_t;
typedef __bf16 bf16x8 __attribute__((ext_vector_type(8)));
typedef float floatx16 __attribute__((ext_vector_type(16)));

// ---------------- prep: wq + pack W fragments ----------------
// wpack layout: (((layer*8 + cg)*16 + kt)*64 + lane)*8 + e
//   cg = col>>5 (0..7), lane = ((k>>3)&1)*32 + (col&31), k = kt*16+((k>>3)&1)*8+e
__global__ __launch_bounds__(256) void prep_kernel(
    const float* __restrict__ q, const float* __restrict__ gw1,
    const float* __restrict__ gb1, const float* __restrict__ g2,
    const float* __restrict__ g3, const float* __restrict__ g4,
    float* __restrict__ wq, bf16_t* __restrict__ wpack)
{
    int blk = blockIdx.x, t = threadIdx.x;
    {
        float acc = gb1[t];
        #pragma unroll
        for (int d = 0; d < 11; d++)
            acc = fmaf(q[blk * 11 + d], gw1[(52 + d) * 256 + t], acc);
        wq[blk * 256 + t] = acc;
    }
    for (int idx = blk * 3072 + t; idx < blk * 3072 + 3072; idx += 256) {
        int layer = idx >> 16;
        int rem = idx & 65535;
        int col = rem & 255;
        int k = rem >> 8;
        const float* gw = (layer == 0) ? g2 : ((layer == 1) ? g3 : g4);
        float v = gw[k * 256 + col];
        int cg = col >> 5, l31 = col & 31;
        int kt = k >> 4, l2 = (k >> 3) & 1, e = k & 7;
        int lane = l2 * 32 + l31;
        wpack[(((layer * 8 + cg) * 16 + kt) * 64 + lane) * 8 + e] = (bf16_t)v;
    }
}

// ---------------- finalize BN stats: one block per channel ----------------
__global__ __launch_bounds__(256) void fin_kernel(
    const float* __restrict__ part, int P, float inv_n,
    const float* __restrict__ gamma, const float* __restrict__ beta,
    float* __restrict__ scsh)
{
    int c = blockIdx.x;   // 24 channels
    int t = threadIdx.x;
    float s1 = 0.f, s2 = 0.f;
    for (int p = t; p < P; p += 256) {
        s1 += part[p * 48 + 2 * c];
        s2 += part[p * 48 + 2 * c + 1];
    }
    #pragma unroll
    for (int off = 32; off > 0; off >>= 1) {
        s1 += __shfl_xor(s1, off);
        s2 += __shfl_xor(s2, off);
    }
    __shared__ float r1[4], r2[4];
    int lane = t & 63, w = t >> 6;
    if (lane == 0) { r1[w] = s1; r2[w] = s2; }
    __syncthreads();
    if (t == 0) {
        float a1 = r1[0] + r1[1] + r1[2] + r1[3];
        float a2 = r2[0] + r2[1] + r2[2] + r2[3];
        float m = a1 * inv_n;
        float var = a2 * inv_n - m * m;
        float sc = gamma[c] * rsqrtf(var + EPS_BN);
        scsh[c] = sc;
        scsh[24 + c] = fmaf(-m, sc, beta[c]);
    }
}

// ---------------- unified conv: stride-2 3x3 + bias + relu (+BN-fold in) ---
template<int CIN, int HOUT, int OY_PER, int CO_PER, bool FOLD>
__global__ __launch_bounds__(256) void conv_kernel(
    const float* __restrict__ in, const float* __restrict__ scsh_in,
    const float* __restrict__ w, const float* __restrict__ bias,
    float* __restrict__ out, float* __restrict__ part_out)
{
    const int HIN = 2 * HOUT, ROWS = 2 * OY_PER + 3, RW = 2 * HOUT + 2;
    const int TILES = HOUT / OY_PER;
    const int WPC = (HOUT * OY_PER) / 64;      // waves per channel-group
    int b = blockIdx.x / TILES, tile = blockIdx.x % TILES;
    int oy0 = tile * OY_PER;
    __shared__ float tin[CIN][ROWS][RW];
    __shared__ float scf[24], shf[24];
    __shared__ float red[4][CO_PER * 2];
    int t = threadIdx.x;
    if (FOLD) {
        if (t < 24) { scf[t] = scsh_in[t]; shf[t] = scsh_in[24 + t]; }
        __syncthreads();
    }
    const int total = CIN * ROWS * RW;
    int iyb = 2 * oy0 - 1;
    #pragma unroll 2
    for (int idx = t; idx < total; idx += 256) {
        int rx = idx % RW;
        int rem = idx / RW;
        int ry = rem % ROWS;
        int ci = rem / ROWS;
        int iy = iyb + ry, ix = rx - 1;
        float v = 0.f;
        if ((unsigned)iy < (unsigned)HIN && (unsigned)ix < (unsigned)HIN) {
            float raw = in[(b * CIN + ci) * HIN * HIN + iy * HIN + ix];
            v = FOLD ? fmaf(raw, scf[ci], shf[ci]) : raw;
        }
        tin[ci][ry][rx] = v;
    }
    __syncthreads();
    int ox = t % HOUT;
    int oyl = (t / HOUT) % OY_PER;
    int cog = t / (HOUT * OY_PER);            // wave-uniform
    const float* wp = w + cog * CO_PER * CIN * 9;
    float acc[CO_PER];
    #pragma unroll
    for (int r = 0; r < CO_PER; r++) acc[r] = bias[cog * CO_PER + r];
    for (int ci = 0; ci < CIN; ci++)
        #pragma unroll
        for (int ky = 0; ky < 3; ky++)
            #pragma unroll
            for (int kx = 0; kx < 3; kx++) {
                float v = tin[ci][2 * oyl + ky][2 * ox + kx];
                #pragma unroll
                for (int r = 0; r < CO_PER; r++)
                    acc[r] = fmaf(v, wp[(r * CIN + ci) * 9 + ky * 3 + kx], acc[r]);
            }
    int oy = oy0 + oyl;
    float s1[CO_PER], s2[CO_PER];
    #pragma unroll
    for (int r = 0; r < CO_PER; r++) {
        float v = fmaxf(acc[r], 0.f);
        out[((b * 24 + cog * CO_PER + r) * HOUT + oy) * HOUT + ox] = v;
        s1[r] = v;
        s2[r] = v * v;
    }
    int lane = t & 63, w_id = t >> 6;
    #pragma unroll
    for (int r = 0; r < CO_PER; r++) {
        float a = s1[r], c2 = s2[r];
        #pragma unroll
        for (int off = 32; off > 0; off >>= 1) {
            a += __shfl_xor(a, off);
            c2 += __shfl_xor(c2, off);
        }
        if (lane == 0) { red[w_id][r * 2] = a; red[w_id][r * 2 + 1] = c2; }
    }
    __syncthreads();
    if (t < 48) {
        int ch = t >> 1, st = t & 1;
        int cg = ch / CO_PER, r = ch % CO_PER;
        float v = 0.f;
        #pragma unroll
        for (int k = 0; k < WPC; k++) v += red[cg * WPC + k][r * 2 + st];
        part_out[blockIdx.x * 48 + t] = v;
    }
}

// ---------------- U/V with BN4 folded (scale/shift precomputed) ------------
__global__ __launch_bounds__(256) void uv_kernel(
    const float* __restrict__ x4, const float* __restrict__ scsh4,
    const float* __restrict__ gw1, float* __restrict__ U, float* __restrict__ V)
{
    int b = blockIdx.x >> 2, n0 = (blockIdx.x & 3) * 16;
    __shared__ float o[16][26];
    int t = threadIdx.x;
    for (int idx = t; idx < 16 * 26; idx += 256) {
        int n = idx / 26, f = idx % 26;
        int ng = n0 + n;
        float val;
        if (f < 24)
            val = fmaf(x4[(b * 24 + f) * 64 + ng], scsh4[f], scsh4[24 + f]);
        else if (f == 24) val = (float)(ng >> 3) * 0.125f;
        else              val = (float)(ng & 7) * 0.125f;
        o[n][f] = val;
    }
    __syncthreads();
    float g1u[26], g1v[26];
    #pragma unroll
    for (int f = 0; f < 26; f++) {
        g1u[f] = gw1[f * 256 + t];
        g1v[f] = gw1[(26 + f) * 256 + t];
    }
    for (int n = 0; n < 16; n++) {
        float u = 0.f, v = 0.f;
        #pragma unroll
        for (int f = 0; f < 26; f++) {
            float of = o[n][f];
            u = fmaf(of, g1u[f], u);
            v = fmaf(of, g1v[f], v);
        }
        int ng = n0 + n;
        U[(b * 64 + ng) * 256 + t] = u;
        V[(b * 64 + ng) * 256 + t] = v;
    }
}

// ---------------- fused pair MLP: 512 thr, 8 waves, 2 i's (128 rows) -------
// wave (wm=wave>>2, wn=wave&3): rows wm*64..+63 (2 mt of 32), cols wn*64..+63
// (2 nt of 32). acc 64 VGPR; B prefetched 1 k-step ahead. 2 blocks/CU,
// 4 waves/SIMD for latency hiding.
__global__ __launch_bounds__(512, 4) void pair_kernel(
    const float* __restrict__ U, const float* __restrict__ V,
    const float* __restrict__ wq, const bf16_t* __restrict__ wpack,
    const float* __restrict__ gb2, const float* __restrict__ gb3,
    const float* __restrict__ gb4, float* __restrict__ partial)
{
    __shared__ __align__(16) bf16_t hA[128][264];
    __shared__ float csum[2][256];
    int blk = blockIdx.x;
    int b = blk >> 5;
    int i0 = (blk & 31) * 2;
    int t = threadIdx.x;

    // ---- build h1: 512 threads, each covers 32 j's x 1 col x 2 i's
    {
        int c = t & 255, jh = t >> 8;
        float wqc = wq[b * 256 + c];
        float uw0 = U[(b * 64 + i0) * 256 + c] + wqc;
        float uw1 = U[(b * 64 + i0 + 1) * 256 + c] + wqc;
        const float* Vb = V + (b * 64) * 256;
        for (int j = jh * 32; j < jh * 32 + 32; j++) {
            float v = Vb[j * 256 + c];
            hA[j][c]      = (bf16_t)fmaxf(uw0 + v, 0.0f);
            hA[64 + j][c] = (bf16_t)fmaxf(uw1 + v, 0.0f);
        }
    }
    __syncthreads();

    int lane = t & 63, wave = t >> 6;
    int wm = wave >> 2, wn = wave & 3;
    int l31 = lane & 31, l2 = lane >> 5;
    int r0 = wm * 64 + l31;
    const floatx16 zero16 = {0.f, 0.f, 0.f, 0.f, 0.f, 0.f, 0.f, 0.f,
                             0.f, 0.f, 0.f, 0.f, 0.f, 0.f, 0.f, 0.f};
    float colsum[2] = {0.f, 0.f};

    #pragma unroll 1
    for (int layer = 0; layer < 3; layer++) {
        const float* bias = (layer == 0) ? gb2 : ((layer == 1) ? gb3 : gb4);
        float bcol[2];
        #pragma unroll
        for (int nt = 0; nt < 2; nt++)
            bcol[nt] = bias[wn * 64 + nt * 32 + l31];

        floatx16 acc[2][2];
        #pragma unroll
        for (int mt = 0; mt < 2; mt++)
            #pragma unroll
            for (int nt = 0; nt < 2; nt++) acc[mt][nt] = zero16;

        // column-group cg = wn*2+nt; frag base (((layer*8+cg)*16+kt)*64+lane)*8
        const bf16_t* W0 = wpack + ((size_t)(layer * 8 + wn * 2) * 16 * 64 + lane) * 8;
        const bf16_t* W1 = W0 + (size_t)16 * 64 * 8;
        bf16x8 Bc[2];
        Bc[0] = *(const bf16x8*)W0;
        Bc[1] = *(const bf16x8*)W1;

        #pragma unroll
        for (int ks = 0; ks < 16; ks++) {
            bf16x8 Bn[2];
            if (ks < 15) {
                Bn[0] = *(const bf16x8*)(W0 + (ks + 1) * 64 * 8);
                Bn[1] = *(const bf16x8*)(W1 + (ks + 1) * 64 * 8);
            }
            bf16x8 a0 = *(const bf16x8*)&hA[r0][ks * 16 + l2 * 8];
            bf16x8 a1 = *(const bf16x8*)&hA[r0 + 32][ks * 16 + l2 * 8];
            #pragma unroll
            for (int nt = 0; nt < 2; nt++) {
                acc[0][nt] = __builtin_amdgcn_mfma_f32_32x32x16_bf16(a0, Bc[nt], acc[0][nt], 0, 0, 0);
                acc[1][nt] = __builtin_amdgcn_mfma_f32_32x32x16_bf16(a1, Bc[nt], acc[1][nt], 0, 0, 0);
            }
            if (ks < 15) { Bc[0] = Bn[0]; Bc[1] = Bn[1]; }
        }

        if (layer < 2) {
            __syncthreads();
            #pragma unroll
            for (int mt = 0; mt < 2; mt++)
                #pragma unroll
                for (int nt = 0; nt < 2; nt++) {
                    int col = wn * 64 + nt * 32 + l31;
                    #pragma unroll
                    for (int reg = 0; reg < 16; reg++) {
                        int row = wm * 64 + mt * 32 + (reg & 3) + 8 * (reg >> 2) + 4 * l2;
                        hA[row][col] = (bf16_t)fmaxf(acc[mt][nt][reg] + bcol[nt], 0.0f);
                    }
                }
            __syncthreads();
        } else {
            #pragma unroll
            for (int nt = 0; nt < 2; nt++) {
                float s = 0.f;
                #pragma unroll
                for (int mt = 0; mt < 2; mt++)
                    #pragma unroll
                    for (int reg = 0; reg < 16; reg++)
                        s += fmaxf(acc[mt][nt][reg] + bcol[nt], 0.0f);
                colsum[nt] += s;
            }
        }
    }

    #pragma unroll
    for (int nt = 0; nt < 2; nt++)
        colsum[nt] += __shfl_xor(colsum[nt], 32);
    if (l2 == 0) {
        #pragma unroll
        for (int nt = 0; nt < 2; nt++)
            csum[wm][wn * 64 + nt * 32 + l31] = colsum[nt];
    }
    __syncthreads();
    if (t < 256)
        partial[blk * 256 + t] = csum[0][t] + csum[1][t];
}

// ---------------- f_phi ----------------
__global__ __launch_bounds__(256) void fphi_kernel(
    const float* __restrict__ partial,
    const float* __restrict__ fw1, const float* __restrict__ fb1,
    const float* __restrict__ fw2, const float* __restrict__ fb2,
    const float* __restrict__ fw3, const float* __restrict__ fb3,
    float* __restrict__ out)
{
    int b = blockIdx.x, t = threadIdx.x;
    __shared__ float g[256], h1[256], h2[256];
    float s = 0.f;
    for (int k = 0; k < 32; k++) s += partial[(b * 32 + k) * 256 + t];
    g[t] = s * (1.0f / 4096.0f);
    __syncthreads();
    float a1 = fb1[t];
    for (int k = 0; k < 256; k++) a1 = fmaf(g[k], fw1[k * 256 + t], a1);
    h1[t] = fmaxf(a1, 0.0f);
    __syncthreads();
    float a2 = fb2[t];
    for (int k = 0; k < 256; k++) a2 = fmaf(h1[k], fw2[k * 256 + t], a2);
    h2[t] = fmaxf(a2, 0.0f);
    __syncthreads();
    if (t < 10) {
        float a3 = fb3[t];
        for (int k = 0; k < 256; k++) a3 = fmaf(h2[k], fw3[k * 10 + t], a3);
        out[b * 10 + t] = a3;
    }
}

extern "C" void kernel_launch(void* const* d_in, const int* in_sizes, int n_in,
                              void* d_out, int out_size, void* d_ws, size_t ws_size,
                              hipStream_t stream)
{
    (void)in_sizes; (void)n_in; (void)out_size; (void)ws_size;
    const float* img = (const float*)d_in[0];
    const float* q   = (const float*)d_in[1];
    const float* cw[4] = {(const float*)d_in[2],  (const float*)d_in[6],
                          (const float*)d_in[10], (const float*)d_in[14]};
    const float* cb[4] = {(const float*)d_in[3],  (const float*)d_in[7],
                          (const float*)d_in[11], (const float*)d_in[15]};
    const float* bg[4] = {(const float*)d_in[4],  (const float*)d_in[8],
                          (const float*)d_in[12], (const float*)d_in[16]};
    const float* bbv[4] = {(const float*)d_in[5],  (const float*)d_in[9],
                           (const float*)d_in[13], (const float*)d_in[17]};
    const float* gw1 = (const float*)d_in[18]; const float* gb1 = (const float*)d_in[19];
    const float* gw2 = (const float*)d_in[20]; const float* gb2 = (const float*)d_in[21];
    const float* gw3 = (const float*)d_in[22]; const float* gb3 = (const float*)d_in[23];
    const float* gw4 = (const float*)d_in[24]; const float* gb4 = (const float*)d_in[25];
    const float* fw1 = (const float*)d_in[26]; const float* fb1 = (const float*)d_in[27];
    const float* fw2 = (const float*)d_in[28]; const float* fb2 = (const float*)d_in[29];
    const float* fw3 = (const float*)d_in[30]; const float* fb3 = (const float*)d_in[31];

    float* ws  = (float*)d_ws;
    float* x1  = ws;                      // 6291456
    float* x2  = x1 + 6291456;            // 1572864
    float* x3  = x2 + 1572864;            // 393216
    float* x4  = x3 + 393216;             // 98304
    float* U   = x4 + 98304;              // 1048576
    float* V   = U + 1048576;             // 1048576
    float* wqv = V + 1048576;             // 16384
    float* part = wqv + 16384;            // 524288
    float* p1  = part + 524288;           // 2048*48
    float* p2  = p1 + 98304;              // 1024*48
    float* p3  = p2 + 49152;              // 256*48
    float* p4  = p3 + 12288;              // 64*48
    float* scsh1 = p4 + 3072;
    float* scsh2 = scsh1 + 48;
    float* scsh3 = scsh2 + 48;
    float* scsh4 = scsh3 + 48;
    bf16_t* wpack = (bf16_t*)(scsh4 + 48);  // 3*65536 bf16

    prep_kernel<<<64, 256, 0, stream>>>(q, gw1, gb1, gw2, gw3, gw4, wqv, wpack);
    conv_kernel<3, 64, 2, 12, false><<<2048, 256, 0, stream>>>(
        img, nullptr, cw[0], cb[0], x1, p1);
    fin_kernel<<<24, 256, 0, stream>>>(p1, 2048, 1.f / 262144.f, bg[0], bbv[0], scsh1);
    conv_kernel<24, 32, 2, 6, true><<<1024, 256, 0, stream>>>(
        x1, scsh1, cw[1], cb[1], x2, p2);
    fin_kernel<<<24, 256, 0, stream>>>(p2, 1024, 1.f / 65536.f, bg[1], bbv[1], scsh2);
    conv_kernel<24, 16, 4, 6, true><<<256, 256, 0, stream>>>(
        x2, scsh2, cw[2], cb[2], x3, p3);
    fin_kernel<<<24, 256, 0, stream>>>(p3, 256, 1.f / 16384.f, bg[2], bbv[2], scsh3);
    conv_kernel<24, 8, 8, 6, true><<<64, 256, 0, stream>>>(
        x3, scsh3, cw[3], cb[3], x4, p4);
    fin_kernel<<<24, 256, 0, stream>>>(p4, 64, 1.f / 4096.f, bg[3], bbv[3], scsh4);
    uv_kernel<<<256, 256, 0, stream>>>(x4, scsh4, gw1, U, V);
    pair_kernel<<<2048, 512, 0, stream>>>(U, V, wqv, wpack, gb2, gb3, gb4, part);
    fphi_kernel<<<64, 256, 0, stream>>>(part, fw1, fb1, fw2, fb2, fw3, fb3,
                                        (float*)d_out);
}